// Round 1
// baseline (1847.446 us; speedup 1.0000x reference)
//
#include <hip/hip_runtime.h>
#include <math.h>

#define NEG 0.1f

__device__ __forceinline__ float lrelu(float x){ return x >= 0.f ? x : NEG*x; }

// ---- pool1: input1 (8,512,128,128) -> p1t (b,n,c), max+mean over 2x2 ----
__global__ __launch_bounds__(256) void k_pool1(const float* __restrict__ in1, float* __restrict__ p1t){
    __shared__ float s[64*68];
    const int b = blockIdx.z, c0 = blockIdx.y*64, pt = blockIdx.x;
    const int y = pt >> 2, xg = pt & 3;
    const int tid = threadIdx.x;
    #pragma unroll
    for (int it = 0; it < 16; ++it){
        int idx = it*256 + tid;
        int cl = idx >> 6, p = idx & 63;
        int r = p >> 5, xx = p & 31;
        float g = in1[((size_t)(b*512 + c0 + cl)*128 + 2*y + r)*128 + xg*32 + xx];
        s[cl*68 + (xx>>1)*4 + r*2 + (xx&1)] = g;   // reorder pixels patch-major
    }
    __syncthreads();
    const int og = tid & 15, j = tid >> 4;
    float out[4];
    #pragma unroll
    for (int ci = 0; ci < 4; ++ci){
        float4 v = *(const float4*)&s[(og*4+ci)*68 + j*4];
        float m = fmaxf(fmaxf(v.x,v.y), fmaxf(v.z,v.w));
        out[ci] = m + (v.x+v.y+v.z+v.w)*0.25f;
    }
    int n = y*64 + xg*16 + j;
    *(float4*)&p1t[(size_t)(b*4096 + n)*512 + c0 + og*4] = make_float4(out[0],out[1],out[2],out[3]);
}

// ---- fused 1x1 conv (w_in: 512x256) + bias + 2x2 max+mean pool -> p2t (b,n,c) ----
__global__ __launch_bounds__(256) void k_convpool(const float* __restrict__ in2, const float* __restrict__ w_in,
                                                  const float* __restrict__ b_in, float* __restrict__ p2t){
    __shared__ float in2s[64*64];   // [ci][pix patch-major]
    __shared__ float wts[64*68];    // [ci][o], padded
    const int b = blockIdx.z, o0 = blockIdx.y*64, pt = blockIdx.x;
    const int y = pt >> 2, xg = pt & 3;
    const int tid = threadIdx.x;
    const int og = tid & 15, j = tid >> 4;   // 16 o-groups x 16 patches
    float acc[4][4] = {};
    for (int cc = 0; cc < 4; ++cc){
        #pragma unroll
        for (int it = 0; it < 16; ++it){
            int idx = it*256 + tid;
            int cl = idx >> 6, p = idx & 63;
            int r = p >> 5, xx = p & 31;
            in2s[cl*64 + (xx>>1)*4 + r*2 + (xx&1)] =
                in2[((size_t)(b*256 + cc*64 + cl)*128 + 2*y + r)*128 + xg*32 + xx];
            wts[p*68 + cl] = 0.f; // placeholder to keep shapes obvious (overwritten below)
            int ol = idx >> 6, cil = idx & 63;
            wts[cil*68 + ol] = w_in[(size_t)(o0 + ol)*256 + cc*64 + cil];
        }
        __syncthreads();
        #pragma unroll 16
        for (int ci = 0; ci < 64; ++ci){
            float4 a  = *(const float4*)&wts[ci*68 + og*4];
            float4 bb = *(const float4*)&in2s[ci*64 + j*4];
            acc[0][0] += a.x*bb.x; acc[0][1] += a.x*bb.y; acc[0][2] += a.x*bb.z; acc[0][3] += a.x*bb.w;
            acc[1][0] += a.y*bb.x; acc[1][1] += a.y*bb.y; acc[1][2] += a.y*bb.z; acc[1][3] += a.y*bb.w;
            acc[2][0] += a.z*bb.x; acc[2][1] += a.z*bb.y; acc[2][2] += a.z*bb.z; acc[2][3] += a.z*bb.w;
            acc[3][0] += a.w*bb.x; acc[3][1] += a.w*bb.y; acc[3][2] += a.w*bb.z; acc[3][3] += a.w*bb.w;
        }
        __syncthreads();
    }
    float res[4];
    #pragma unroll
    for (int oi = 0; oi < 4; ++oi){
        float m = fmaxf(fmaxf(acc[oi][0],acc[oi][1]), fmaxf(acc[oi][2],acc[oi][3]));
        float mean = (acc[oi][0]+acc[oi][1]+acc[oi][2]+acc[oi][3])*0.25f;
        res[oi] = m + mean + 2.0f*b_in[o0 + og*4 + oi];   // max(x+b)+mean(x+b) = max+mean+2b
    }
    int n = y*64 + xg*16 + j;
    *(float4*)&p2t[(size_t)(b*4096 + n)*512 + o0 + og*4] = make_float4(res[0],res[1],res[2],res[3]);
}

// ---- per-(b,n) row: q = focus(lrelu(p1+pos1)/softplus(scale)) in-place; k likewise -> kfoc ----
__global__ __launch_bounds__(256) void k_rows(float* __restrict__ p1t, const float* __restrict__ p2t,
                                              const float* __restrict__ pos1, const float* __restrict__ pos2,
                                              const float* __restrict__ scale_param, float* __restrict__ kfoc){
    const int n = blockIdx.x, b = blockIdx.y;
    const int tid = threadIdx.x;
    const size_t base = (size_t)(b*4096 + n)*512;
    __shared__ float red[4][4];
    float qv[2], kv_[2];
    float pq2=0.f, pq6=0.f, pk2=0.f, pk6=0.f;
    #pragma unroll
    for (int i = 0; i < 2; ++i){
        int c = tid + i*256;
        float sp = scale_param[c];
        float spl = fmaxf(sp, 0.f) + log1pf(expf(-fabsf(sp)));  // softplus
        float inv = 1.0f / spl;
        float q = lrelu(p1t[base + c] + pos1[n*512 + c]) * inv;
        float k = lrelu(p2t[base + c] + pos2[n*512 + c]) * inv;
        qv[i] = q; kv_[i] = k;
        float q2 = q*q, k2 = k*k;
        pq2 += q2; pq6 += q2*q2*q2;
        pk2 += k2; pk6 += k2*k2*k2;
    }
    #pragma unroll
    for (int off = 32; off > 0; off >>= 1){
        pq2 += __shfl_xor(pq2, off);
        pq6 += __shfl_xor(pq6, off);
        pk2 += __shfl_xor(pk2, off);
        pk6 += __shfl_xor(pk6, off);
    }
    int wave = tid >> 6;
    if ((tid & 63) == 0){ red[wave][0]=pq2; red[wave][1]=pq6; red[wave][2]=pk2; red[wave][3]=pk6; }
    __syncthreads();
    float sq2 = red[0][0]+red[1][0]+red[2][0]+red[3][0];
    float sq6 = red[0][1]+red[1][1]+red[2][1]+red[3][1];
    float sk2 = red[0][2]+red[1][2]+red[2][2]+red[3][2];
    float sk6 = red[0][3]+red[1][3]+red[2][3]+red[3][3];
    float fq = sqrtf(sq2/sq6);
    float fk = sqrtf(sk2/sk6);
    #pragma unroll
    for (int i = 0; i < 2; ++i){
        int c = tid + i*256;
        p1t[base + c]  = qv[i]*qv[i]*qv[i]*fq;
        kfoc[base + c] = kv_[i]*kv_[i]*kv_[i]*fk;
    }
}

// ---- kv[b,h,d,e] = sum_n k[b,n,h*32+d]*v[b,n,h*32+e] / N  (n-split + atomics) ----
__global__ __launch_bounds__(256) void k_kv(const float* __restrict__ kfoc, const float* __restrict__ p2t,
                                            float* __restrict__ kv){
    __shared__ float ks[512], vs[512];
    const int nc = blockIdx.x, h = blockIdx.y, b = blockIdx.z;
    const int tid = threadIdx.x;
    const int d = tid >> 3, eb = (tid & 7) * 4;
    float acc[4] = {0.f,0.f,0.f,0.f};
    for (int s = 0; s < 16; ++s){
        int n0 = nc*256 + s*16;
        #pragma unroll
        for (int p = 0; p < 2; ++p){
            int i = p*256 + tid;
            int nn = i >> 5, cs = i & 31;
            size_t g = (size_t)(b*4096 + n0 + nn)*512 + h*32 + cs;
            ks[i] = kfoc[g];
            vs[i] = p2t[g];
        }
        __syncthreads();
        #pragma unroll
        for (int nn = 0; nn < 16; ++nn){
            float kd = ks[nn*32 + d];
            float4 vv = *(const float4*)&vs[nn*32 + eb];
            acc[0] += kd*vv.x; acc[1] += kd*vv.y; acc[2] += kd*vv.z; acc[3] += kd*vv.w;
        }
        __syncthreads();
    }
    float* dst = &kv[((size_t)(b*16 + h)*32 + d)*32 + eb];
    const float sc = 1.0f/4096.0f;
    atomicAdd(dst+0, acc[0]*sc);
    atomicAdd(dst+1, acc[1]*sc);
    atomicAdd(dst+2, acc[2]*sc);
    atomicAdd(dst+3, acc[3]*sc);
}

// ---- attn[b,n,h*32+e] = sum_d q[n,d]*kv[d,e] + lrelu(sum_d v[n,d]*w_v[e,d] + b_v[e]) ----
__global__ __launch_bounds__(256) void k_attn(const float* __restrict__ qfoc, const float* __restrict__ p2t,
                                              const float* __restrict__ kv, const float* __restrict__ w_v,
                                              const float* __restrict__ b_v, float* __restrict__ attn){
    __shared__ float kvs[1024];      // [d][e]
    __shared__ float wvsT[32*36];    // [d][e] padded (w_v transposed)
    __shared__ float qsl[64*32];
    __shared__ float vsl[64*32];
    const int nt = blockIdx.x, h = blockIdx.y, b = blockIdx.z;
    const int tid = threadIdx.x;
    #pragma unroll
    for (int it = 0; it < 4; ++it){
        int i = it*256 + tid;
        kvs[i] = kv[(size_t)(b*16 + h)*1024 + i];
        int e_ = i >> 5, d_ = i & 31;
        wvsT[d_*36 + e_] = w_v[e_*32 + d_];
    }
    #pragma unroll
    for (int it = 0; it < 8; ++it){
        int i = it*256 + tid;
        int nn = i >> 5, dd = i & 31;
        size_t g = (size_t)(b*4096 + nt*64 + nn)*512 + h*32 + dd;
        qsl[i] = qfoc[g];
        vsl[i] = p2t[g];
    }
    __syncthreads();
    const int e0 = (tid & 7)*4, ng = tid >> 3;
    float4 bv = make_float4(b_v[e0], b_v[e0+1], b_v[e0+2], b_v[e0+3]);
    #pragma unroll
    for (int half = 0; half < 2; ++half){
        int nn = ng + half*32;
        float xa[4] = {0.f,0.f,0.f,0.f}, va[4] = {0.f,0.f,0.f,0.f};
        #pragma unroll
        for (int dq = 0; dq < 8; ++dq){
            float4 q4 = *(const float4*)&qsl[nn*32 + dq*4];
            float4 v4 = *(const float4*)&vsl[nn*32 + dq*4];
            float qarr[4] = {q4.x,q4.y,q4.z,q4.w};
            float varr[4] = {v4.x,v4.y,v4.z,v4.w};
            #pragma unroll
            for (int l = 0; l < 4; ++l){
                int d = dq*4 + l;
                float4 kvv = *(const float4*)&kvs[d*32 + e0];
                float4 wvv = *(const float4*)&wvsT[d*36 + e0];
                xa[0] += qarr[l]*kvv.x; xa[1] += qarr[l]*kvv.y; xa[2] += qarr[l]*kvv.z; xa[3] += qarr[l]*kvv.w;
                va[0] += varr[l]*wvv.x; va[1] += varr[l]*wvv.y; va[2] += varr[l]*wvv.z; va[3] += varr[l]*wvv.w;
            }
        }
        float4 o;
        o.x = xa[0] + lrelu(va[0] + bv.x);
        o.y = xa[1] + lrelu(va[1] + bv.y);
        o.z = xa[2] + lrelu(va[2] + bv.z);
        o.w = xa[3] + lrelu(va[3] + bv.w);
        *(float4*)&attn[(size_t)(b*4096 + nt*64 + nn)*512 + h*32 + e0] = o;
    }
}

// ---- bilinear 64->128 align_corners + sigmoid; attn (b,n,c) -> out (b,c,128,128) ----
__global__ __launch_bounds__(256) void k_up(const float* __restrict__ attn, float* __restrict__ out){
    const int tid = threadIdx.x;
    const int row = blockIdx.x*2 + (tid >> 7);   // (b*512+c)*128 + yo
    const int xo = tid & 127;
    const int yo = row & 127;
    const int bc = row >> 7;
    const int c = bc & 511, b = bc >> 9;
    const float r = 63.0f/127.0f;
    float ty = yo * r, tx = xo * r;
    int y0 = (int)ty; y0 = y0 > 62 ? 62 : y0;
    int x0 = (int)tx; x0 = x0 > 62 ? 62 : x0;
    float wy = ty - (float)y0, wx = tx - (float)x0;
    size_t nb = (size_t)b*4096;
    float a00 = attn[(nb + y0*64     + x0    )*512 + c];
    float a01 = attn[(nb + y0*64     + x0 + 1)*512 + c];
    float a10 = attn[(nb + (y0+1)*64 + x0    )*512 + c];
    float a11 = attn[(nb + (y0+1)*64 + x0 + 1)*512 + c];
    float v = (a00*(1.f-wy) + a10*wy)*(1.f-wx) + (a01*(1.f-wy) + a11*wy)*wx;
    out[(size_t)row*128 + xo] = 1.0f/(1.0f + expf(-v));
}

extern "C" void kernel_launch(void* const* d_in, const int* in_sizes, int n_in,
                              void* d_out, int out_size, void* d_ws, size_t ws_size,
                              hipStream_t stream){
    const float* in1  = (const float*)d_in[0];
    const float* in2  = (const float*)d_in[1];
    const float* w_in = (const float*)d_in[2];
    const float* b_in = (const float*)d_in[3];
    const float* w_v  = (const float*)d_in[4];
    const float* b_v  = (const float*)d_in[5];
    const float* scp  = (const float*)d_in[6];
    const float* pos1 = (const float*)d_in[7];
    const float* pos2 = (const float*)d_in[8];
    float* out = (float*)d_out;
    float* ws  = (float*)d_ws;

    const size_t PBUF = (size_t)8*4096*512;   // 16,777,216 floats per (b,n,c) buffer
    float* p1t  = ws;               // becomes qfoc in-place after k_rows
    float* p2t  = ws + PBUF;        // pooled projected input2 == v
    float* kfoc = ws + 2*PBUF;      // focused k; reused as attn after k_kv
    float* kv   = ws + 3*PBUF;      // 8*16*32*32 floats

    hipMemsetAsync(kv, 0, (size_t)8*16*32*32*sizeof(float), stream);
    k_pool1   <<<dim3(256,8,8), 256, 0, stream>>>(in1, p1t);
    k_convpool<<<dim3(256,8,8), 256, 0, stream>>>(in2, w_in, b_in, p2t);
    k_rows    <<<dim3(4096,8),  256, 0, stream>>>(p1t, p2t, pos1, pos2, scp, kfoc);
    k_kv      <<<dim3(16,16,8), 256, 0, stream>>>(kfoc, p2t, kv);
    k_attn    <<<dim3(64,16,8), 256, 0, stream>>>(p1t, p2t, kv, w_v, b_v, kfoc);
    k_up      <<<262144,        256, 0, stream>>>(kfoc, out);
}

// Round 2
// 910.901 us; speedup vs baseline: 2.0282x; 2.0282x over previous
//
#include <hip/hip_runtime.h>
#include <math.h>

#define NEG 0.1f

typedef __attribute__((ext_vector_type(8))) short short8;
typedef __attribute__((ext_vector_type(4))) float f32x4;

__device__ __forceinline__ float lrelu(float x){ return x >= 0.f ? x : NEG*x; }

// round-to-nearest-even fp32 -> bf16
__device__ __forceinline__ unsigned short f2bf(float f){
    unsigned u = __float_as_uint(f);
    return (unsigned short)((u + 0x7FFFu + ((u>>16)&1u)) >> 16);
}
__device__ __forceinline__ unsigned pk2(float lo, float hi){
    return (unsigned)f2bf(lo) | ((unsigned)f2bf(hi) << 16);
}

// ---- pool1: input1 (8,512,128,128) -> p1t (b,n,c), max+mean over 2x2 ----
__global__ __launch_bounds__(256) void k_pool1(const float* __restrict__ in1, float* __restrict__ p1t){
    __shared__ float s[64*68];
    const int b = blockIdx.z, c0 = blockIdx.y*64, pt = blockIdx.x;
    const int y = pt >> 2, xg = pt & 3;
    const int tid = threadIdx.x;
    #pragma unroll
    for (int it = 0; it < 16; ++it){
        int idx = it*256 + tid;
        int cl = idx >> 6, p = idx & 63;
        int r = p >> 5, xx = p & 31;
        float g = in1[((size_t)(b*512 + c0 + cl)*128 + 2*y + r)*128 + xg*32 + xx];
        s[cl*68 + (xx>>1)*4 + r*2 + (xx&1)] = g;   // patch-major reorder
    }
    __syncthreads();
    const int og = tid & 15, j = tid >> 4;
    float out[4];
    #pragma unroll
    for (int ci = 0; ci < 4; ++ci){
        float4 v = *(const float4*)&s[(og*4+ci)*68 + j*4];
        float m = fmaxf(fmaxf(v.x,v.y), fmaxf(v.z,v.w));
        out[ci] = m + (v.x+v.y+v.z+v.w)*0.25f;
    }
    int n = y*64 + xg*16 + j;
    *(float4*)&p1t[(size_t)(b*4096 + n)*512 + c0 + og*4] = make_float4(out[0],out[1],out[2],out[3]);
}

// ---- fused 1x1 conv + bias + 2x2 max+mean pool via bf16 MFMA -> p2t (b,n,c) ----
// Block: 128 o-channels x 128 pixels (2 rows x 64 cols), K=256, BK=64.
// LDS layout [row][k] bf16, row stride 32 dwords, granule XOR-swizzle:
//   dword addr = row*32 + ((granule ^ ((row>>1)&7))<<2) + (k2&3)
__global__ __launch_bounds__(256) void k_convpool(const float* __restrict__ in2, const float* __restrict__ w_in,
                                                  const float* __restrict__ b_in, float* __restrict__ p2t){
    __shared__ unsigned As[128*33];   // K-loop uses stride 32; epilogue reuses as float[128][33]
    __shared__ unsigned Bs[128*32];
    const int b = blockIdx.z, o0 = blockIdx.y*128;
    const int y = blockIdx.x >> 1, xg = blockIdx.x & 1;
    const int tid = threadIdx.x;
    const int lane = tid & 63, w = tid >> 6;
    const int col = lane & 15, q = lane >> 4;

    f32x4 acc[2][8];
    #pragma unroll
    for (int mt=0; mt<2; ++mt)
        #pragma unroll
        for (int nt=0; nt<8; ++nt) acc[mt][nt] = (f32x4){0.f,0.f,0.f,0.f};

    const int a_o8 = tid >> 3;                 // o row within 32-row pass
    const int a_kg = tid & 7;                  // k-granule 0..7
    const int b_c4 = tid & 15, b_r = (tid>>4)&1, b_kg = tid>>5;  // b_kg 0..7
    const int b_n = b_r*64 + b_c4*4;

    for (int kb = 0; kb < 4; ++kb){
        __syncthreads();
        // ---- stage A: 128 o x 64 k (w_in is L2-hot) ----
        #pragma unroll
        for (int pass=0; pass<4; ++pass){
            int o = pass*32 + a_o8;
            const float* src = &w_in[(size_t)(o0+o)*256 + kb*64 + a_kg*8];
            float4 v0 = *(const float4*)src;
            float4 v1 = *(const float4*)(src+4);
            uint4 d;
            d.x = pk2(v0.x, v0.y); d.y = pk2(v0.z, v0.w);
            d.z = pk2(v1.x, v1.y); d.w = pk2(v1.z, v1.w);
            *(uint4*)&As[o*32 + ((a_kg ^ ((o>>1)&7))<<2)] = d;
        }
        // ---- stage B: 128 pixels x 64 k, with register transpose ----
        float r[8][4];
        #pragma unroll
        for (int kk=0; kk<8; ++kk){
            int k = kb*64 + b_kg*8 + kk;
            float4 v = *(const float4*)&in2[((size_t)(b*256 + k)*128 + 2*y + b_r)*128 + xg*64 + b_c4*4];
            r[kk][0]=v.x; r[kk][1]=v.y; r[kk][2]=v.z; r[kk][3]=v.w;
        }
        #pragma unroll
        for (int i=0; i<4; ++i){
            int n = b_n + i;
            uint4 d;
            d.x = pk2(r[0][i], r[1][i]); d.y = pk2(r[2][i], r[3][i]);
            d.z = pk2(r[4][i], r[5][i]); d.w = pk2(r[6][i], r[7][i]);
            *(uint4*)&Bs[n*32 + ((b_kg ^ ((n>>1)&7))<<2)] = d;
        }
        __syncthreads();
        // ---- MFMA: wave w covers o rows [w*32, w*32+32), all 128 pixels ----
        #pragma unroll
        for (int ks=0; ks<2; ++ks){
            int g = ks*4 + q;
            short8 af[2], bf[8];
            #pragma unroll
            for (int mt=0; mt<2; ++mt){
                int m = w*32 + mt*16 + col;
                af[mt] = *(const short8*)&As[m*32 + ((g ^ ((m>>1)&7))<<2)];
            }
            #pragma unroll
            for (int nt=0; nt<8; ++nt){
                int n = nt*16 + col;
                bf[nt] = *(const short8*)&Bs[n*32 + ((g ^ ((n>>1)&7))<<2)];
            }
            #pragma unroll
            for (int mt=0; mt<2; ++mt)
                #pragma unroll
                for (int nt=0; nt<8; ++nt)
                    acc[mt][nt] = __builtin_amdgcn_mfma_f32_16x16x32_bf16(af[mt], bf[nt], acc[mt][nt], 0,0,0);
        }
    }
    __syncthreads();
    // ---- 2x2 pool: rows = acc pairs (nt, nt+4), cols = lane pairs (shfl_xor 1) ----
    float* outs = (float*)As;   // reuse, stride 33
    #pragma unroll
    for (int mt=0; mt<2; ++mt){
        #pragma unroll
        for (int nt=0; nt<4; ++nt){
            #pragma unroll
            for (int reg=0; reg<4; ++reg){
                float a = acc[mt][nt][reg], bb = acc[mt][nt+4][reg];
                float mx = fmaxf(a, bb), sm = a + bb;
                float mx2 = fmaxf(mx, __shfl_xor(mx, 1));
                float sm2 = sm + __shfl_xor(sm, 1);
                if ((lane & 1) == 0){
                    int p = nt*8 + (col>>1);
                    int o = w*32 + mt*16 + q*4 + reg;
                    outs[o*33 + p] = mx2 + sm2*0.25f;
                }
            }
        }
    }
    __syncthreads();
    // ---- coalesced write: p2t[(b,n,c)], bias 2*b_in (max+mean of x+b) ----
    const int o4 = tid & 31, pp = tid >> 5;
    #pragma unroll
    for (int pass=0; pass<4; ++pass){
        int p = pass*8 + pp;
        int n = y*64 + xg*32 + p;
        float4 vv;
        vv.x = outs[(o4*4+0)*33 + p] + 2.0f*b_in[o0+o4*4+0];
        vv.y = outs[(o4*4+1)*33 + p] + 2.0f*b_in[o0+o4*4+1];
        vv.z = outs[(o4*4+2)*33 + p] + 2.0f*b_in[o0+o4*4+2];
        vv.w = outs[(o4*4+3)*33 + p] + 2.0f*b_in[o0+o4*4+3];
        *(float4*)&p2t[(size_t)(b*4096 + n)*512 + o0 + o4*4] = vv;
    }
}

// ---- per-(b,n) row: q = focus(lrelu(p1+pos1)/softplus(scale)) in-place; k -> kfoc ----
__global__ __launch_bounds__(256) void k_rows(float* __restrict__ p1t, const float* __restrict__ p2t,
                                              const float* __restrict__ pos1, const float* __restrict__ pos2,
                                              const float* __restrict__ scale_param, float* __restrict__ kfoc){
    const int n = blockIdx.x, b = blockIdx.y;
    const int tid = threadIdx.x;
    const size_t base = (size_t)(b*4096 + n)*512;
    __shared__ float red[4][4];
    float qv[2], kv_[2];
    float pq2=0.f, pq6=0.f, pk2_=0.f, pk6=0.f;
    #pragma unroll
    for (int i = 0; i < 2; ++i){
        int c = tid + i*256;
        float sp = scale_param[c];
        float spl = fmaxf(sp, 0.f) + log1pf(expf(-fabsf(sp)));  // softplus
        float inv = 1.0f / spl;
        float q = lrelu(p1t[base + c] + pos1[n*512 + c]) * inv;
        float k = lrelu(p2t[base + c] + pos2[n*512 + c]) * inv;
        qv[i] = q; kv_[i] = k;
        float q2 = q*q, k2 = k*k;
        pq2 += q2; pq6 += q2*q2*q2;
        pk2_ += k2; pk6 += k2*k2*k2;
    }
    #pragma unroll
    for (int off = 32; off > 0; off >>= 1){
        pq2 += __shfl_xor(pq2, off);
        pq6 += __shfl_xor(pq6, off);
        pk2_ += __shfl_xor(pk2_, off);
        pk6 += __shfl_xor(pk6, off);
    }
    int wave = tid >> 6;
    if ((tid & 63) == 0){ red[wave][0]=pq2; red[wave][1]=pq6; red[wave][2]=pk2_; red[wave][3]=pk6; }
    __syncthreads();
    float sq2 = red[0][0]+red[1][0]+red[2][0]+red[3][0];
    float sq6 = red[0][1]+red[1][1]+red[2][1]+red[3][1];
    float sk2 = red[0][2]+red[1][2]+red[2][2]+red[3][2];
    float sk6 = red[0][3]+red[1][3]+red[2][3]+red[3][3];
    float fq = sqrtf(sq2/sq6);
    float fk = sqrtf(sk2/sk6);
    #pragma unroll
    for (int i = 0; i < 2; ++i){
        int c = tid + i*256;
        p1t[base + c]  = qv[i]*qv[i]*qv[i]*fq;
        kfoc[base + c] = kv_[i]*kv_[i]*kv_[i]*fk;
    }
}

// ---- kv[b,h,d,e] = sum_n k[b,n,h*32+d]*v[b,n,h*32+e] / N  (n-split + atomics) ----
__global__ __launch_bounds__(256) void k_kv(const float* __restrict__ kfoc, const float* __restrict__ p2t,
                                            float* __restrict__ kv){
    __shared__ float ks[512], vs[512];
    const int nc = blockIdx.x, h = blockIdx.y, b = blockIdx.z;
    const int tid = threadIdx.x;
    const int d = tid >> 3, eb = (tid & 7) * 4;
    float acc[4] = {0.f,0.f,0.f,0.f};
    for (int s = 0; s < 16; ++s){
        int n0 = nc*256 + s*16;
        #pragma unroll
        for (int p = 0; p < 2; ++p){
            int i = p*256 + tid;
            int nn = i >> 5, cs = i & 31;
            size_t g = (size_t)(b*4096 + n0 + nn)*512 + h*32 + cs;
            ks[i] = kfoc[g];
            vs[i] = p2t[g];
        }
        __syncthreads();
        #pragma unroll
        for (int nn = 0; nn < 16; ++nn){
            float kd = ks[nn*32 + d];
            float4 vv = *(const float4*)&vs[nn*32 + eb];
            acc[0] += kd*vv.x; acc[1] += kd*vv.y; acc[2] += kd*vv.z; acc[3] += kd*vv.w;
        }
        __syncthreads();
    }
    float* dst = &kv[((size_t)(b*16 + h)*32 + d)*32 + eb];
    const float sc = 1.0f/4096.0f;
    atomicAdd(dst+0, acc[0]*sc);
    atomicAdd(dst+1, acc[1]*sc);
    atomicAdd(dst+2, acc[2]*sc);
    atomicAdd(dst+3, acc[3]*sc);
}

// ---- attn: x = q.kv + lrelu(v.w_v^T + b_v); OUTPUT TRANSPOSED to (b, c, n) ----
__global__ __launch_bounds__(256) void k_attn(const float* __restrict__ qfoc, const float* __restrict__ p2t,
                                              const float* __restrict__ kv, const float* __restrict__ w_v,
                                              const float* __restrict__ b_v, float* __restrict__ attn){
    __shared__ float kvs[1024];      // [d][e]
    __shared__ float wvsT[32*36];    // [d][e] padded
    __shared__ float qsl[64*32];
    __shared__ float vsl[64*32];
    __shared__ float to[32*66];      // [c][n] transpose staging, padded
    const int nt = blockIdx.x, h = blockIdx.y, b = blockIdx.z;
    const int tid = threadIdx.x;
    #pragma unroll
    for (int it = 0; it < 4; ++it){
        int i = it*256 + tid;
        kvs[i] = kv[(size_t)(b*16 + h)*1024 + i];
        int e_ = i >> 5, d_ = i & 31;
        wvsT[d_*36 + e_] = w_v[e_*32 + d_];
    }
    #pragma unroll
    for (int it = 0; it < 8; ++it){
        int i = it*256 + tid;
        int nn = i >> 5, dd = i & 31;
        size_t g = (size_t)(b*4096 + nt*64 + nn)*512 + h*32 + dd;
        qsl[i] = qfoc[g];
        vsl[i] = p2t[g];
    }
    __syncthreads();
    const int e0 = (tid & 7)*4, ng = tid >> 3;
    float4 bv = make_float4(b_v[e0], b_v[e0+1], b_v[e0+2], b_v[e0+3]);
    #pragma unroll
    for (int half = 0; half < 2; ++half){
        int nn = ng + half*32;
        float xa[4] = {0.f,0.f,0.f,0.f}, va[4] = {0.f,0.f,0.f,0.f};
        #pragma unroll
        for (int dq = 0; dq < 8; ++dq){
            float4 q4 = *(const float4*)&qsl[nn*32 + dq*4];
            float4 v4 = *(const float4*)&vsl[nn*32 + dq*4];
            float qarr[4] = {q4.x,q4.y,q4.z,q4.w};
            float varr[4] = {v4.x,v4.y,v4.z,v4.w};
            #pragma unroll
            for (int l = 0; l < 4; ++l){
                int d = dq*4 + l;
                float4 kvv = *(const float4*)&kvs[d*32 + e0];
                float4 wvv = *(const float4*)&wvsT[d*36 + e0];
                xa[0] += qarr[l]*kvv.x; xa[1] += qarr[l]*kvv.y; xa[2] += qarr[l]*kvv.z; xa[3] += qarr[l]*kvv.w;
                va[0] += varr[l]*wvv.x; va[1] += varr[l]*wvv.y; va[2] += varr[l]*wvv.z; va[3] += varr[l]*wvv.w;
            }
        }
        to[(e0+0)*66 + nn] = xa[0] + lrelu(va[0] + bv.x);
        to[(e0+1)*66 + nn] = xa[1] + lrelu(va[1] + bv.y);
        to[(e0+2)*66 + nn] = xa[2] + lrelu(va[2] + bv.z);
        to[(e0+3)*66 + nn] = xa[3] + lrelu(va[3] + bv.w);
    }
    __syncthreads();
    const int cc = tid >> 3, n0 = (tid & 7)*8;
    size_t obase = ((size_t)(b*512) + h*32 + cc)*4096 + nt*64 + n0;
    float4 w0, w1;
    w0.x = to[cc*66+n0+0]; w0.y = to[cc*66+n0+1]; w0.z = to[cc*66+n0+2]; w0.w = to[cc*66+n0+3];
    w1.x = to[cc*66+n0+4]; w1.y = to[cc*66+n0+5]; w1.z = to[cc*66+n0+6]; w1.w = to[cc*66+n0+7];
    *(float4*)&attn[obase]   = w0;
    *(float4*)&attn[obase+4] = w1;
}

// ---- bilinear 64->128 align_corners + sigmoid; attn (b,c,n) -> out (b,c,128,128) ----
__global__ __launch_bounds__(256) void k_up(const float* __restrict__ attn, float* __restrict__ out){
    const int tid = threadIdx.x;
    const int row = blockIdx.x*2 + (tid >> 7);   // (b*512+c)*128 + yo
    const int xo = tid & 127;
    const int yo = row & 127;
    const int bc = row >> 7;
    const float r = 63.0f/127.0f;
    float ty = yo * r, tx = xo * r;
    int y0 = (int)ty; y0 = y0 > 62 ? 62 : y0;
    int x0 = (int)tx; x0 = x0 > 62 ? 62 : x0;
    float wy = ty - (float)y0, wx = tx - (float)x0;
    const float* ap = attn + (size_t)bc*4096;
    float a00 = ap[y0*64 + x0],       a01 = ap[y0*64 + x0 + 1];
    float a10 = ap[(y0+1)*64 + x0],   a11 = ap[(y0+1)*64 + x0 + 1];
    float v = (a00*(1.f-wy) + a10*wy)*(1.f-wx) + (a01*(1.f-wy) + a11*wy)*wx;
    out[(size_t)row*128 + xo] = 1.0f/(1.0f + expf(-v));
}

extern "C" void kernel_launch(void* const* d_in, const int* in_sizes, int n_in,
                              void* d_out, int out_size, void* d_ws, size_t ws_size,
                              hipStream_t stream){
    const float* in1  = (const float*)d_in[0];
    const float* in2  = (const float*)d_in[1];
    const float* w_in = (const float*)d_in[2];
    const float* b_in = (const float*)d_in[3];
    const float* w_v  = (const float*)d_in[4];
    const float* b_v  = (const float*)d_in[5];
    const float* scp  = (const float*)d_in[6];
    const float* pos1 = (const float*)d_in[7];
    const float* pos2 = (const float*)d_in[8];
    float* out = (float*)d_out;
    float* ws  = (float*)d_ws;

    const size_t PBUF = (size_t)8*4096*512;
    float* p1t  = ws;               // becomes qfoc in-place after k_rows
    float* p2t  = ws + PBUF;        // pooled projected input2 == v
    float* kfoc = ws + 2*PBUF;      // focused k; reused as attn (b,c,n) after k_kv
    float* kv   = ws + 3*PBUF;

    hipMemsetAsync(kv, 0, (size_t)8*16*32*32*sizeof(float), stream);
    k_pool1   <<<dim3(256,8,8), 256, 0, stream>>>(in1, p1t);
    k_convpool<<<dim3(128,4,8), 256, 0, stream>>>(in2, w_in, b_in, p2t);
    k_rows    <<<dim3(4096,8),  256, 0, stream>>>(p1t, p2t, pos1, pos2, scp, kfoc);
    k_kv      <<<dim3(16,16,8), 256, 0, stream>>>(kfoc, p2t, kv);
    k_attn    <<<dim3(64,16,8), 256, 0, stream>>>(p1t, p2t, kv, w_v, b_v, kfoc);
    k_up      <<<262144,        256, 0, stream>>>(kfoc, out);
}

// Round 3
// 843.718 us; speedup vs baseline: 2.1896x; 1.0796x over previous
//
#include <hip/hip_runtime.h>
#include <math.h>

#define NEG 0.1f

typedef __attribute__((ext_vector_type(8))) short short8;
typedef __attribute__((ext_vector_type(4))) float f32x4;

__device__ __forceinline__ float lrelu(float x){ return x >= 0.f ? x : NEG*x; }

// round-to-nearest-even fp32 -> bf16 (raw u16)
__device__ __forceinline__ unsigned short f2bf(float f){
    unsigned u = __float_as_uint(f);
    return (unsigned short)((u + 0x7FFFu + ((u>>16)&1u)) >> 16);
}
__device__ __forceinline__ unsigned pk2(float lo, float hi){
    return (unsigned)f2bf(lo) | ((unsigned)f2bf(hi) << 16);
}
__device__ __forceinline__ float bflo(unsigned u){ return __uint_as_float(u << 16); }
__device__ __forceinline__ float bfhi(unsigned u){ return __uint_as_float(u & 0xFFFF0000u); }

// ---- pool1: input1 (8,512,128,128) -> p1t bf16 (b,n,c), max+mean over 2x2 ----
__global__ __launch_bounds__(256) void k_pool1(const float* __restrict__ in1, unsigned short* __restrict__ p1t){
    __shared__ float s[64*68];
    const int b = blockIdx.z, c0 = blockIdx.y*64, pt = blockIdx.x;
    const int y = pt >> 2, xg = pt & 3;
    const int tid = threadIdx.x;
    #pragma unroll
    for (int it = 0; it < 16; ++it){
        int idx = it*256 + tid;
        int cl = idx >> 6, p = idx & 63;
        int r = p >> 5, xx = p & 31;
        float g = in1[((size_t)(b*512 + c0 + cl)*128 + 2*y + r)*128 + xg*32 + xx];
        s[cl*68 + (xx>>1)*4 + r*2 + (xx&1)] = g;   // patch-major reorder
    }
    __syncthreads();
    const int og = tid & 15, j = tid >> 4;
    float out[4];
    #pragma unroll
    for (int ci = 0; ci < 4; ++ci){
        float4 v = *(const float4*)&s[(og*4+ci)*68 + j*4];
        float m = fmaxf(fmaxf(v.x,v.y), fmaxf(v.z,v.w));
        out[ci] = m + (v.x+v.y+v.z+v.w)*0.25f;
    }
    int n = y*64 + xg*16 + j;
    uint2 d; d.x = pk2(out[0],out[1]); d.y = pk2(out[2],out[3]);
    *(uint2*)&p1t[(size_t)(b*4096 + n)*512 + c0 + og*4] = d;
}

// ---- fused 1x1 conv + bias + 2x2 max+mean pool via bf16 MFMA -> p2t bf16 (b,n,c) ----
__global__ __launch_bounds__(256) void k_convpool(const float* __restrict__ in2, const float* __restrict__ w_in,
                                                  const float* __restrict__ b_in, unsigned short* __restrict__ p2t){
    __shared__ unsigned As[128*33];   // K-loop stride 32; epilogue reuses as float[128][33]
    __shared__ unsigned Bs[128*32];
    const int b = blockIdx.z, o0 = blockIdx.y*128;
    const int y = blockIdx.x >> 1, xg = blockIdx.x & 1;
    const int tid = threadIdx.x;
    const int lane = tid & 63, w = tid >> 6;
    const int col = lane & 15, q = lane >> 4;

    f32x4 acc[2][8];
    #pragma unroll
    for (int mt=0; mt<2; ++mt)
        #pragma unroll
        for (int nt=0; nt<8; ++nt) acc[mt][nt] = (f32x4){0.f,0.f,0.f,0.f};

    const int a_o8 = tid >> 3;
    const int a_kg = tid & 7;
    const int b_c4 = tid & 15, b_r = (tid>>4)&1, b_kg = tid>>5;
    const int b_n = b_r*64 + b_c4*4;

    for (int kb = 0; kb < 4; ++kb){
        __syncthreads();
        #pragma unroll
        for (int pass=0; pass<4; ++pass){
            int o = pass*32 + a_o8;
            const float* src = &w_in[(size_t)(o0+o)*256 + kb*64 + a_kg*8];
            float4 v0 = *(const float4*)src;
            float4 v1 = *(const float4*)(src+4);
            uint4 d;
            d.x = pk2(v0.x, v0.y); d.y = pk2(v0.z, v0.w);
            d.z = pk2(v1.x, v1.y); d.w = pk2(v1.z, v1.w);
            *(uint4*)&As[o*32 + ((a_kg ^ ((o>>1)&7))<<2)] = d;
        }
        float r[8][4];
        #pragma unroll
        for (int kk=0; kk<8; ++kk){
            int k = kb*64 + b_kg*8 + kk;
            float4 v = *(const float4*)&in2[((size_t)(b*256 + k)*128 + 2*y + b_r)*128 + xg*64 + b_c4*4];
            r[kk][0]=v.x; r[kk][1]=v.y; r[kk][2]=v.z; r[kk][3]=v.w;
        }
        #pragma unroll
        for (int i=0; i<4; ++i){
            int n = b_n + i;
            uint4 d;
            d.x = pk2(r[0][i], r[1][i]); d.y = pk2(r[2][i], r[3][i]);
            d.z = pk2(r[4][i], r[5][i]); d.w = pk2(r[6][i], r[7][i]);
            *(uint4*)&Bs[n*32 + ((b_kg ^ ((n>>1)&7))<<2)] = d;
        }
        __syncthreads();
        #pragma unroll
        for (int ks=0; ks<2; ++ks){
            int g = ks*4 + q;
            short8 af[2], bf[8];
            #pragma unroll
            for (int mt=0; mt<2; ++mt){
                int m = w*32 + mt*16 + col;
                af[mt] = *(const short8*)&As[m*32 + ((g ^ ((m>>1)&7))<<2)];
            }
            #pragma unroll
            for (int nt=0; nt<8; ++nt){
                int n = nt*16 + col;
                bf[nt] = *(const short8*)&Bs[n*32 + ((g ^ ((n>>1)&7))<<2)];
            }
            #pragma unroll
            for (int mt=0; mt<2; ++mt)
                #pragma unroll
                for (int nt=0; nt<8; ++nt)
                    acc[mt][nt] = __builtin_amdgcn_mfma_f32_16x16x32_bf16(af[mt], bf[nt], acc[mt][nt], 0,0,0);
        }
    }
    __syncthreads();
    float* outs = (float*)As;   // stride 33
    #pragma unroll
    for (int mt=0; mt<2; ++mt){
        #pragma unroll
        for (int nt=0; nt<4; ++nt){
            #pragma unroll
            for (int reg=0; reg<4; ++reg){
                float a = acc[mt][nt][reg], bb = acc[mt][nt+4][reg];
                float mx = fmaxf(a, bb), sm = a + bb;
                float mx2 = fmaxf(mx, __shfl_xor(mx, 1));
                float sm2 = sm + __shfl_xor(sm, 1);
                if ((lane & 1) == 0){
                    int p = nt*8 + (col>>1);
                    int o = w*32 + mt*16 + q*4 + reg;
                    outs[o*33 + p] = mx2 + sm2*0.25f;
                }
            }
        }
    }
    __syncthreads();
    const int o4 = tid & 31, pp = tid >> 5;
    #pragma unroll
    for (int pass=0; pass<4; ++pass){
        int p = pass*8 + pp;
        int n = y*64 + xg*32 + p;
        float v0 = outs[(o4*4+0)*33 + p] + 2.0f*b_in[o0+o4*4+0];
        float v1 = outs[(o4*4+1)*33 + p] + 2.0f*b_in[o0+o4*4+1];
        float v2 = outs[(o4*4+2)*33 + p] + 2.0f*b_in[o0+o4*4+2];
        float v3 = outs[(o4*4+3)*33 + p] + 2.0f*b_in[o0+o4*4+3];
        uint2 d; d.x = pk2(v0,v1); d.y = pk2(v2,v3);
        *(uint2*)&p2t[(size_t)(b*4096 + n)*512 + o0 + o4*4] = d;
    }
}

// ---- per-(b,n) row: q=focus(lrelu(p1+pos1)/spl) in-place bf16; k likewise -> kfoc bf16 ----
__global__ __launch_bounds__(256) void k_rows(unsigned* __restrict__ p1u, const unsigned* __restrict__ p2u,
                                              const float* __restrict__ pos1, const float* __restrict__ pos2,
                                              const float* __restrict__ scale_param, unsigned* __restrict__ kfu){
    const int n = blockIdx.x, b = blockIdx.y;
    const int tid = threadIdx.x;
    const size_t baseu = (size_t)(b*4096 + n)*256;   // uint index (2 bf16 per uint)
    const int c0 = tid*2;
    __shared__ float red[4][4];
    unsigned u1 = p1u[baseu + tid];
    unsigned u2 = p2u[baseu + tid];
    float2 po1 = *(const float2*)&pos1[n*512 + c0];
    float2 po2 = *(const float2*)&pos2[n*512 + c0];
    float2 scv = *(const float2*)&scale_param[c0];
    float qv[2], kv_[2];
    float pq2=0.f, pq6=0.f, pk2_=0.f, pk6=0.f;
    {
        float sp0 = scv.x, sp1 = scv.y;
        float inv0 = 1.0f/(fmaxf(sp0,0.f) + log1pf(expf(-fabsf(sp0))));
        float inv1 = 1.0f/(fmaxf(sp1,0.f) + log1pf(expf(-fabsf(sp1))));
        float q0 = lrelu(bflo(u1) + po1.x) * inv0;
        float q1 = lrelu(bfhi(u1) + po1.y) * inv1;
        float k0 = lrelu(bflo(u2) + po2.x) * inv0;
        float k1 = lrelu(bfhi(u2) + po2.y) * inv1;
        qv[0]=q0; qv[1]=q1; kv_[0]=k0; kv_[1]=k1;
        float a;
        a = q0*q0; pq2 += a; pq6 += a*a*a;
        a = q1*q1; pq2 += a; pq6 += a*a*a;
        a = k0*k0; pk2_ += a; pk6 += a*a*a;
        a = k1*k1; pk2_ += a; pk6 += a*a*a;
    }
    #pragma unroll
    for (int off = 32; off > 0; off >>= 1){
        pq2 += __shfl_xor(pq2, off);
        pq6 += __shfl_xor(pq6, off);
        pk2_ += __shfl_xor(pk2_, off);
        pk6 += __shfl_xor(pk6, off);
    }
    int wave = tid >> 6;
    if ((tid & 63) == 0){ red[wave][0]=pq2; red[wave][1]=pq6; red[wave][2]=pk2_; red[wave][3]=pk6; }
    __syncthreads();
    float sq2 = red[0][0]+red[1][0]+red[2][0]+red[3][0];
    float sq6 = red[0][1]+red[1][1]+red[2][1]+red[3][1];
    float sk2 = red[0][2]+red[1][2]+red[2][2]+red[3][2];
    float sk6 = red[0][3]+red[1][3]+red[2][3]+red[3][3];
    float fq = sqrtf(sq2/sq6);
    float fk = sqrtf(sk2/sk6);
    p1u[baseu + tid] = pk2(qv[0]*qv[0]*qv[0]*fq, qv[1]*qv[1]*qv[1]*fq);
    kfu[baseu + tid] = pk2(kv_[0]*kv_[0]*kv_[0]*fk, kv_[1]*kv_[1]*kv_[1]*fk);
}

// ---- kv[b,h,d,e] = sum_n k*v / N  (n-split + atomics), bf16 inputs ----
__global__ __launch_bounds__(256) void k_kv(const unsigned* __restrict__ kfu, const unsigned* __restrict__ p2u,
                                            float* __restrict__ kv){
    __shared__ float ks[512], vs[512];
    const int nc = blockIdx.x, h = blockIdx.y, b = blockIdx.z;
    const int tid = threadIdx.x;
    const int d = tid >> 3, eb = (tid & 7) * 4;
    const int nn_ld = tid >> 4, cp = tid & 15;
    float acc[4] = {0.f,0.f,0.f,0.f};
    for (int s = 0; s < 16; ++s){
        int n0 = nc*256 + s*16;
        size_t g = (size_t)(b*4096 + n0 + nn_ld)*256 + h*16 + cp;
        unsigned ku = kfu[g], vu = p2u[g];
        ks[nn_ld*32 + cp*2]   = bflo(ku);
        ks[nn_ld*32 + cp*2+1] = bfhi(ku);
        vs[nn_ld*32 + cp*2]   = bflo(vu);
        vs[nn_ld*32 + cp*2+1] = bfhi(vu);
        __syncthreads();
        #pragma unroll
        for (int nn = 0; nn < 16; ++nn){
            float kd = ks[nn*32 + d];
            float4 vv = *(const float4*)&vs[nn*32 + eb];
            acc[0] += kd*vv.x; acc[1] += kd*vv.y; acc[2] += kd*vv.z; acc[3] += kd*vv.w;
        }
        __syncthreads();
    }
    float* dst = &kv[((size_t)(b*16 + h)*32 + d)*32 + eb];
    const float sc = 1.0f/4096.0f;
    atomicAdd(dst+0, acc[0]*sc);
    atomicAdd(dst+1, acc[1]*sc);
    atomicAdd(dst+2, acc[2]*sc);
    atomicAdd(dst+3, acc[3]*sc);
}

// ---- attn: x = q.kv + lrelu(v.w_v^T + b_v); output (b,c,n) bf16 ----
__global__ __launch_bounds__(256) void k_attn(const unsigned* __restrict__ qfu, const unsigned* __restrict__ p2u,
                                              const float* __restrict__ kv, const float* __restrict__ w_v,
                                              const float* __restrict__ b_v, unsigned short* __restrict__ attn){
    __shared__ float kvs[1024];
    __shared__ float wvsT[32*36];
    __shared__ float qsl[64*32];
    __shared__ float vsl[64*32];
    __shared__ float to[32*66];
    const int nt = blockIdx.x, h = blockIdx.y, b = blockIdx.z;
    const int tid = threadIdx.x;
    #pragma unroll
    for (int it = 0; it < 4; ++it){
        int i = it*256 + tid;
        kvs[i] = kv[(size_t)(b*16 + h)*1024 + i];
        int e_ = i >> 5, d_ = i & 31;
        wvsT[d_*36 + e_] = w_v[e_*32 + d_];
    }
    #pragma unroll
    for (int it = 0; it < 4; ++it){
        int i = it*256 + tid;
        int nn = i >> 4, cp = i & 15;
        size_t g = (size_t)(b*4096 + nt*64 + nn)*256 + h*16 + cp;
        unsigned qu = qfu[g], vu = p2u[g];
        qsl[nn*32 + cp*2]   = bflo(qu);
        qsl[nn*32 + cp*2+1] = bfhi(qu);
        vsl[nn*32 + cp*2]   = bflo(vu);
        vsl[nn*32 + cp*2+1] = bfhi(vu);
    }
    __syncthreads();
    const int e0 = (tid & 7)*4, ng = tid >> 3;
    float4 bv = make_float4(b_v[e0], b_v[e0+1], b_v[e0+2], b_v[e0+3]);
    #pragma unroll
    for (int half = 0; half < 2; ++half){
        int nn = ng + half*32;
        float xa[4] = {0.f,0.f,0.f,0.f}, va[4] = {0.f,0.f,0.f,0.f};
        #pragma unroll
        for (int dq = 0; dq < 8; ++dq){
            float4 q4 = *(const float4*)&qsl[nn*32 + dq*4];
            float4 v4 = *(const float4*)&vsl[nn*32 + dq*4];
            float qarr[4] = {q4.x,q4.y,q4.z,q4.w};
            float varr[4] = {v4.x,v4.y,v4.z,v4.w};
            #pragma unroll
            for (int l = 0; l < 4; ++l){
                int d = dq*4 + l;
                float4 kvv = *(const float4*)&kvs[d*32 + e0];
                float4 wvv = *(const float4*)&wvsT[d*36 + e0];
                xa[0] += qarr[l]*kvv.x; xa[1] += qarr[l]*kvv.y; xa[2] += qarr[l]*kvv.z; xa[3] += qarr[l]*kvv.w;
                va[0] += varr[l]*wvv.x; va[1] += varr[l]*wvv.y; va[2] += varr[l]*wvv.z; va[3] += varr[l]*wvv.w;
            }
        }
        to[(e0+0)*66 + nn] = xa[0] + lrelu(va[0] + bv.x);
        to[(e0+1)*66 + nn] = xa[1] + lrelu(va[1] + bv.y);
        to[(e0+2)*66 + nn] = xa[2] + lrelu(va[2] + bv.z);
        to[(e0+3)*66 + nn] = xa[3] + lrelu(va[3] + bv.w);
    }
    __syncthreads();
    const int cc = tid >> 3, n0 = (tid & 7)*8;
    uint4 d;
    d.x = pk2(to[cc*66+n0+0], to[cc*66+n0+1]);
    d.y = pk2(to[cc*66+n0+2], to[cc*66+n0+3]);
    d.z = pk2(to[cc*66+n0+4], to[cc*66+n0+5]);
    d.w = pk2(to[cc*66+n0+6], to[cc*66+n0+7]);
    *(uint4*)&attn[((size_t)(b*512) + h*32 + cc)*4096 + nt*64 + n0] = d;
}

// ---- bilinear 64->128 align_corners + sigmoid; attn bf16 (b,c,n) -> out fp32 ----
// block: one (bc, y-quarter); stage 18 attn rows in LDS; 16 px/thread, float4 stores
__global__ __launch_bounds__(256) void k_up(const unsigned* __restrict__ attn_u, float* __restrict__ out){
    __shared__ float sA[18*65];
    const int qy = blockIdx.x;            // 0..3
    const int bc = blockIdx.y;            // 0..4095
    const int tid = threadIdx.x;
    const int ybase = (qy*32*63)/127;     // 0,15,31,47
    const size_t sb = (size_t)bc*2048;    // uints per bc slice
    for (int i = tid; i < 576; i += 256){
        int r = i >> 5, cu = i & 31;
        int ridx = ybase + r; if (ridx > 63) ridx = 63;
        unsigned u = attn_u[sb + ridx*32 + cu];
        sA[r*65 + cu*2]   = bflo(u);
        sA[r*65 + cu*2+1] = bfhi(u);
    }
    __syncthreads();
    const float rr = 63.0f/127.0f;
    const int ro = tid >> 3, cbase = tid & 7;
    const int yo = qy*32 + ro;
    float ty = yo * rr;
    int y0 = (int)ty; y0 = y0 > 62 ? 62 : y0;
    float wy = ty - (float)y0;
    const float* ra = &sA[(y0 - ybase)*65];
    const float* rb = ra + 65;
    float* orow = &out[((size_t)bc*128 + yo)*128];
    #pragma unroll
    for (int t = 0; t < 4; ++t){
        int xo0 = (cbase + t*8)*4;
        float4 o;
        float* op = (float*)&o;
        #pragma unroll
        for (int j = 0; j < 4; ++j){
            int xo = xo0 + j;
            float tx = xo * rr;
            int x0 = (int)tx; x0 = x0 > 62 ? 62 : x0;
            float wx = tx - (float)x0;
            float a00 = ra[x0], a01 = ra[x0+1];
            float a10 = rb[x0], a11 = rb[x0+1];
            float v = (a00*(1.f-wy) + a10*wy)*(1.f-wx) + (a01*(1.f-wy) + a11*wy)*wx;
            op[j] = 1.0f/(1.0f + expf(-v));
        }
        *(float4*)&orow[xo0] = o;
    }
}

extern "C" void kernel_launch(void* const* d_in, const int* in_sizes, int n_in,
                              void* d_out, int out_size, void* d_ws, size_t ws_size,
                              hipStream_t stream){
    const float* in1  = (const float*)d_in[0];
    const float* in2  = (const float*)d_in[1];
    const float* w_in = (const float*)d_in[2];
    const float* b_in = (const float*)d_in[3];
    const float* w_v  = (const float*)d_in[4];
    const float* b_v  = (const float*)d_in[5];
    const float* scp  = (const float*)d_in[6];
    const float* pos1 = (const float*)d_in[7];
    const float* pos2 = (const float*)d_in[8];
    float* out = (float*)d_out;
    char* ws  = (char*)d_ws;

    const size_t PBYTES = (size_t)8*4096*512*2;   // bf16 buffer bytes (33.5 MB)
    unsigned short* p1t  = (unsigned short*)ws;                 // qfoc in-place after k_rows
    unsigned short* p2t  = (unsigned short*)(ws + PBYTES);      // pooled projected input2 == v
    unsigned short* kfoc = (unsigned short*)(ws + 2*PBYTES);    // focused k; reused as attn (b,c,n)
    float*          kvb  = (float*)(ws + 3*PBYTES);

    hipMemsetAsync(kvb, 0, (size_t)8*16*32*32*sizeof(float), stream);
    k_pool1   <<<dim3(256,8,8), 256, 0, stream>>>(in1, p1t);
    k_convpool<<<dim3(128,4,8), 256, 0, stream>>>(in2, w_in, b_in, p2t);
    k_rows    <<<dim3(4096,8),  256, 0, stream>>>((unsigned*)p1t, (const unsigned*)p2t, pos1, pos2, scp, (unsigned*)kfoc);
    k_kv      <<<dim3(16,16,8), 256, 0, stream>>>((const unsigned*)kfoc, (const unsigned*)p2t, kvb);
    k_attn    <<<dim3(64,16,8), 256, 0, stream>>>((const unsigned*)p1t, (const unsigned*)p2t, kvb, w_v, b_v, kfoc);
    k_up      <<<dim3(4,4096),  256, 0, stream>>>((const unsigned*)kfoc, out);
}

// Round 4
// 813.570 us; speedup vs baseline: 2.2708x; 1.0371x over previous
//
#include <hip/hip_runtime.h>
#include <hip/hip_bf16.h>
#include <math.h>

#define NEG 0.1f

typedef __attribute__((ext_vector_type(8))) short short8;
typedef __attribute__((ext_vector_type(4))) float f32x4;

__device__ __forceinline__ float lrelu(float x){ return x >= 0.f ? x : NEG*x; }

// fp32x2 -> packed bf16x2 (RTNE) via HIP intrinsic (lowers to v_cvt_pk_bf16_f32 on gfx950)
__device__ __forceinline__ unsigned pk2(float lo, float hi){
    __hip_bfloat162 h = __float22bfloat162_rn(make_float2(lo, hi));
    union { __hip_bfloat162 h2; unsigned u; } cv; cv.h2 = h;
    return cv.u;
}
__device__ __forceinline__ float bflo(unsigned u){ return __uint_as_float(u << 16); }
__device__ __forceinline__ float bfhi(unsigned u){ return __uint_as_float(u & 0xFFFF0000u); }

// ---- prepass: w_in (512x256 fp32) -> bf16 row-major ----
__global__ __launch_bounds__(256) void k_wprep(const float* __restrict__ w_in, unsigned* __restrict__ wbf_u){
    int idx8 = (blockIdx.x*256 + threadIdx.x)*8;
    float4 v0 = *(const float4*)&w_in[idx8];
    float4 v1 = *(const float4*)&w_in[idx8+4];
    uint4 d;
    d.x = pk2(v0.x, v0.y); d.y = pk2(v0.z, v0.w);
    d.z = pk2(v1.x, v1.y); d.w = pk2(v1.z, v1.w);
    *(uint4*)&wbf_u[idx8>>1] = d;
}

// ---- pool1: input1 (8,512,128,128) -> p1t bf16 (b,n,c); no LDS, float2 loads ----
__global__ __launch_bounds__(256) void k_pool1(const float* __restrict__ in1, unsigned* __restrict__ p1u){
    const int y = blockIdx.x, cg = blockIdx.y, b = blockIdx.z;
    const int tid = threadIdx.x;
    const int x = tid & 63, w = tid >> 6;
    const int cbase = cg*32 + w*8;
    const float2* iv = (const float2*)in1;
    float out[8];
    #pragma unroll
    for (int j = 0; j < 8; ++j){
        int c = cbase + j;
        size_t r0 = (size_t)(b*512 + c)*8192 + (2*y)*64 + x;
        float2 a = iv[r0];
        float2 bb = iv[r0 + 64];
        float m = fmaxf(fmaxf(a.x,a.y), fmaxf(bb.x,bb.y));
        out[j] = m + (a.x+a.y+bb.x+bb.y)*0.25f;
    }
    uint4 d;
    d.x = pk2(out[0],out[1]); d.y = pk2(out[2],out[3]);
    d.z = pk2(out[4],out[5]); d.w = pk2(out[6],out[7]);
    int n = y*64 + x;
    *(uint4*)&p1u[(size_t)(b*4096 + n)*256 + cg*16 + w*4] = d;
}

// ---- fused 1x1 conv + bias + 2x2 max+mean pool via bf16 MFMA -> p2t bf16 (b,n,c) ----
__global__ __launch_bounds__(256) void k_convpool(const float* __restrict__ in2, const unsigned* __restrict__ wbf_u,
                                                  const float* __restrict__ b_in, unsigned short* __restrict__ p2t){
    __shared__ unsigned As[128*33];   // K-loop stride 32; epilogue reuses as float[128][33]
    __shared__ unsigned Bs[128*32];
    const int b = blockIdx.z, o0 = blockIdx.y*128;
    const int y = blockIdx.x >> 1, xg = blockIdx.x & 1;
    const int tid = threadIdx.x;
    const int lane = tid & 63, w = tid >> 6;
    const int col = lane & 15, q = lane >> 4;

    f32x4 acc[2][8];
    #pragma unroll
    for (int mt=0; mt<2; ++mt)
        #pragma unroll
        for (int nt=0; nt<8; ++nt) acc[mt][nt] = (f32x4){0.f,0.f,0.f,0.f};

    const int a_o8 = tid >> 3;
    const int a_kg = tid & 7;
    const int b_c4 = tid & 15, b_r = (tid>>4)&1, b_kg = tid>>5;
    const int b_n = b_r*64 + b_c4*4;

    for (int kb = 0; kb < 4; ++kb){
        __syncthreads();
        // ---- stage A: bf16 copy (pre-converted), swizzled ----
        #pragma unroll
        for (int pass=0; pass<4; ++pass){
            int o = pass*32 + a_o8;
            uint4 d = *(const uint4*)&wbf_u[((size_t)(o0+o)*256 + kb*64 + a_kg*8) >> 1];
            *(uint4*)&As[o*32 + ((a_kg ^ ((o>>1)&7))<<2)] = d;
        }
        // ---- stage B: 128 pixels x 64 k, register transpose + packed cvt ----
        float r[8][4];
        #pragma unroll
        for (int kk=0; kk<8; ++kk){
            int k = kb*64 + b_kg*8 + kk;
            float4 v = *(const float4*)&in2[((size_t)(b*256 + k)*128 + 2*y + b_r)*128 + xg*64 + b_c4*4];
            r[kk][0]=v.x; r[kk][1]=v.y; r[kk][2]=v.z; r[kk][3]=v.w;
        }
        #pragma unroll
        for (int i=0; i<4; ++i){
            int n = b_n + i;
            uint4 d;
            d.x = pk2(r[0][i], r[1][i]); d.y = pk2(r[2][i], r[3][i]);
            d.z = pk2(r[4][i], r[5][i]); d.w = pk2(r[6][i], r[7][i]);
            *(uint4*)&Bs[n*32 + ((b_kg ^ ((n>>1)&7))<<2)] = d;
        }
        __syncthreads();
        #pragma unroll
        for (int ks=0; ks<2; ++ks){
            int g = ks*4 + q;
            short8 af[2], bf[8];
            #pragma unroll
            for (int mt=0; mt<2; ++mt){
                int m = w*32 + mt*16 + col;
                af[mt] = *(const short8*)&As[m*32 + ((g ^ ((m>>1)&7))<<2)];
            }
            #pragma unroll
            for (int nt=0; nt<8; ++nt){
                int n = nt*16 + col;
                bf[nt] = *(const short8*)&Bs[n*32 + ((g ^ ((n>>1)&7))<<2)];
            }
            #pragma unroll
            for (int mt=0; mt<2; ++mt)
                #pragma unroll
                for (int nt=0; nt<8; ++nt)
                    acc[mt][nt] = __builtin_amdgcn_mfma_f32_16x16x32_bf16(af[mt], bf[nt], acc[mt][nt], 0,0,0);
        }
    }
    __syncthreads();
    float* outs = (float*)As;   // stride 33
    #pragma unroll
    for (int mt=0; mt<2; ++mt){
        #pragma unroll
        for (int nt=0; nt<4; ++nt){
            #pragma unroll
            for (int reg=0; reg<4; ++reg){
                float a = acc[mt][nt][reg], bb = acc[mt][nt+4][reg];
                float mx = fmaxf(a, bb), sm = a + bb;
                float mx2 = fmaxf(mx, __shfl_xor(mx, 1));
                float sm2 = sm + __shfl_xor(sm, 1);
                if ((lane & 1) == 0){
                    int p = nt*8 + (col>>1);
                    int o = w*32 + mt*16 + q*4 + reg;
                    outs[o*33 + p] = mx2 + sm2*0.25f;
                }
            }
        }
    }
    __syncthreads();
    const int o4 = tid & 31, pp = tid >> 5;
    #pragma unroll
    for (int pass=0; pass<4; ++pass){
        int p = pass*8 + pp;
        int n = y*64 + xg*32 + p;
        float v0 = outs[(o4*4+0)*33 + p] + 2.0f*b_in[o0+o4*4+0];
        float v1 = outs[(o4*4+1)*33 + p] + 2.0f*b_in[o0+o4*4+1];
        float v2 = outs[(o4*4+2)*33 + p] + 2.0f*b_in[o0+o4*4+2];
        float v3 = outs[(o4*4+3)*33 + p] + 2.0f*b_in[o0+o4*4+3];
        uint2 d; d.x = pk2(v0,v1); d.y = pk2(v2,v3);
        *(uint2*)&p2t[(size_t)(b*4096 + n)*512 + o0 + o4*4] = d;
    }
}

// ---- rows: q=focus(lrelu(p1+pos1)/spl) in-place bf16; k likewise -> kfoc. 2 rows/block ----
__global__ __launch_bounds__(256) void k_rows(unsigned* __restrict__ p1u, const unsigned* __restrict__ p2u,
                                              const float* __restrict__ pos1, const float* __restrict__ pos2,
                                              const float* __restrict__ scale_param, unsigned* __restrict__ kfu){
    const int b = blockIdx.y;
    const int tid = threadIdx.x;
    const int half = tid >> 7, t = tid & 127;
    const int n = blockIdx.x*2 + half;
    const int c0 = t*4;
    const size_t base2 = (size_t)(b*4096 + n)*128;   // uint2 index
    __shared__ float red[4][4];
    uint2 u1 = *(const uint2*)&p1u[base2*2 + t*2];
    uint2 u2 = *(const uint2*)&p2u[base2*2 + t*2];
    float4 po1 = *(const float4*)&pos1[n*512 + c0];
    float4 po2 = *(const float4*)&pos2[n*512 + c0];
    float4 scv = *(const float4*)&scale_param[c0];
    float qv[4], kv_[4];
    float pq2=0.f, pq6=0.f, pk2_=0.f, pk6=0.f;
    {
        float p1a[4] = {bflo(u1.x), bfhi(u1.x), bflo(u1.y), bfhi(u1.y)};
        float p2a[4] = {bflo(u2.x), bfhi(u2.x), bflo(u2.y), bfhi(u2.y)};
        float poa1[4] = {po1.x,po1.y,po1.z,po1.w};
        float poa2[4] = {po2.x,po2.y,po2.z,po2.w};
        float sca[4] = {scv.x,scv.y,scv.z,scv.w};
        #pragma unroll
        for (int j = 0; j < 4; ++j){
            float sp = sca[j];
            float inv = 1.0f/(fmaxf(sp,0.f) + log1pf(expf(-fabsf(sp))));
            float qq = lrelu(p1a[j] + poa1[j]) * inv;
            float kk = lrelu(p2a[j] + poa2[j]) * inv;
            qv[j]=qq; kv_[j]=kk;
            float a;
            a = qq*qq; pq2 += a; pq6 += a*a*a;
            a = kk*kk; pk2_ += a; pk6 += a*a*a;
        }
    }
    #pragma unroll
    for (int off = 32; off > 0; off >>= 1){
        pq2 += __shfl_xor(pq2, off);
        pq6 += __shfl_xor(pq6, off);
        pk2_ += __shfl_xor(pk2_, off);
        pk6 += __shfl_xor(pk6, off);
    }
    int wave = tid >> 6;
    if ((tid & 63) == 0){ red[wave][0]=pq2; red[wave][1]=pq6; red[wave][2]=pk2_; red[wave][3]=pk6; }
    __syncthreads();
    float sq2 = red[2*half][0]+red[2*half+1][0];
    float sq6 = red[2*half][1]+red[2*half+1][1];
    float sk2 = red[2*half][2]+red[2*half+1][2];
    float sk6 = red[2*half][3]+red[2*half+1][3];
    float fq = sqrtf(sq2/sq6);
    float fk = sqrtf(sk2/sk6);
    uint2 dq, dk;
    dq.x = pk2(qv[0]*qv[0]*qv[0]*fq, qv[1]*qv[1]*qv[1]*fq);
    dq.y = pk2(qv[2]*qv[2]*qv[2]*fq, qv[3]*qv[3]*qv[3]*fq);
    dk.x = pk2(kv_[0]*kv_[0]*kv_[0]*fk, kv_[1]*kv_[1]*kv_[1]*fk);
    dk.y = pk2(kv_[2]*kv_[2]*kv_[2]*fk, kv_[3]*kv_[3]*kv_[3]*fk);
    *(uint2*)&p1u[base2*2 + t*2] = dq;
    *(uint2*)&kfu[base2*2 + t*2] = dk;
}

// ---- kv[b,h,d,e] = sum_n k*v / N ; one barrier, packed-bf16 LDS stage ----
__global__ __launch_bounds__(256) void k_kv(const unsigned* __restrict__ kfu, const unsigned* __restrict__ p2u,
                                            float* __restrict__ kv){
    __shared__ unsigned ksu[4096], vsu[4096];
    const int nc = blockIdx.x, h = blockIdx.y, b = blockIdx.z;
    const int tid = threadIdx.x;
    #pragma unroll
    for (int it = 0; it < 16; ++it){
        int i = it*256 + tid;
        int n = i >> 4, u = i & 15;
        size_t g = (size_t)(b*4096 + nc*256 + n)*256 + h*16 + u;
        ksu[i] = kfu[g];
        vsu[i] = p2u[g];
    }
    __syncthreads();
    const int d = tid >> 3, e2 = (tid & 7)*2;
    const unsigned kmaskhi = (d & 1) ? 1u : 0u;
    float acc[4] = {0.f,0.f,0.f,0.f};
    #pragma unroll 8
    for (int n = 0; n < 256; ++n){
        unsigned ku = ksu[n*16 + (d>>1)];
        float kd = kmaskhi ? bfhi(ku) : bflo(ku);
        uint2 vv = *(const uint2*)&vsu[n*16 + e2];
        acc[0] += kd*bflo(vv.x); acc[1] += kd*bfhi(vv.x);
        acc[2] += kd*bflo(vv.y); acc[3] += kd*bfhi(vv.y);
    }
    float* dst = &kv[((size_t)(b*16 + h)*32 + d)*32 + (tid&7)*4];
    const float sc = 1.0f/4096.0f;
    atomicAdd(dst+0, acc[0]*sc);
    atomicAdd(dst+1, acc[1]*sc);
    atomicAdd(dst+2, acc[2]*sc);
    atomicAdd(dst+3, acc[3]*sc);
}

// ---- attn: x = q.kv + lrelu(v.w_v^T + b_v); output (b,c,n) bf16 ----
__global__ __launch_bounds__(256) void k_attn(const unsigned* __restrict__ qfu, const unsigned* __restrict__ p2u,
                                              const float* __restrict__ kv, const float* __restrict__ w_v,
                                              const float* __restrict__ b_v, unsigned short* __restrict__ attn){
    __shared__ float kvs[1024];
    __shared__ float wvsT[32*36];
    __shared__ float qsl[64*32];
    __shared__ float vsl[64*32];
    __shared__ float to[32*66];
    const int nt = blockIdx.x, h = blockIdx.y, b = blockIdx.z;
    const int tid = threadIdx.x;
    #pragma unroll
    for (int it = 0; it < 4; ++it){
        int i = it*256 + tid;
        kvs[i] = kv[(size_t)(b*16 + h)*1024 + i];
        int e_ = i >> 5, d_ = i & 31;
        wvsT[d_*36 + e_] = w_v[e_*32 + d_];
    }
    #pragma unroll
    for (int it = 0; it < 4; ++it){
        int i = it*256 + tid;
        int nn = i >> 4, cp = i & 15;
        size_t g = (size_t)(b*4096 + nt*64 + nn)*256 + h*16 + cp;
        unsigned qu = qfu[g], vu = p2u[g];
        qsl[nn*32 + cp*2]   = bflo(qu);
        qsl[nn*32 + cp*2+1] = bfhi(qu);
        vsl[nn*32 + cp*2]   = bflo(vu);
        vsl[nn*32 + cp*2+1] = bfhi(vu);
    }
    __syncthreads();
    const int e0 = (tid & 7)*4, ng = tid >> 3;
    float4 bv = make_float4(b_v[e0], b_v[e0+1], b_v[e0+2], b_v[e0+3]);
    #pragma unroll
    for (int half = 0; half < 2; ++half){
        int nn = ng + half*32;
        float xa[4] = {0.f,0.f,0.f,0.f}, va[4] = {0.f,0.f,0.f,0.f};
        #pragma unroll
        for (int dq = 0; dq < 8; ++dq){
            float4 q4 = *(const float4*)&qsl[nn*32 + dq*4];
            float4 v4 = *(const float4*)&vsl[nn*32 + dq*4];
            float qarr[4] = {q4.x,q4.y,q4.z,q4.w};
            float varr[4] = {v4.x,v4.y,v4.z,v4.w};
            #pragma unroll
            for (int l = 0; l < 4; ++l){
                int d = dq*4 + l;
                float4 kvv = *(const float4*)&kvs[d*32 + e0];
                float4 wvv = *(const float4*)&wvsT[d*36 + e0];
                xa[0] += qarr[l]*kvv.x; xa[1] += qarr[l]*kvv.y; xa[2] += qarr[l]*kvv.z; xa[3] += qarr[l]*kvv.w;
                va[0] += varr[l]*wvv.x; va[1] += varr[l]*wvv.y; va[2] += varr[l]*wvv.z; va[3] += varr[l]*wvv.w;
            }
        }
        to[(e0+0)*66 + nn] = xa[0] + lrelu(va[0] + bv.x);
        to[(e0+1)*66 + nn] = xa[1] + lrelu(va[1] + bv.y);
        to[(e0+2)*66 + nn] = xa[2] + lrelu(va[2] + bv.z);
        to[(e0+3)*66 + nn] = xa[3] + lrelu(va[3] + bv.w);
    }
    __syncthreads();
    const int cc = tid >> 3, n0 = (tid & 7)*8;
    uint4 d;
    d.x = pk2(to[cc*66+n0+0], to[cc*66+n0+1]);
    d.y = pk2(to[cc*66+n0+2], to[cc*66+n0+3]);
    d.z = pk2(to[cc*66+n0+4], to[cc*66+n0+5]);
    d.w = pk2(to[cc*66+n0+6], to[cc*66+n0+7]);
    *(uint4*)&attn[((size_t)(b*512) + h*32 + cc)*4096 + nt*64 + n0] = d;
}

// ---- bilinear 64->128 align_corners + sigmoid; attn bf16 (b,c,n) -> out fp32 ----
__global__ __launch_bounds__(256) void k_up(const unsigned* __restrict__ attn_u, float* __restrict__ out){
    __shared__ float sA[18*65];
    const int qy = blockIdx.x;            // 0..3
    const int bc = blockIdx.y;            // 0..4095
    const int tid = threadIdx.x;
    const int ybase = (qy*32*63)/127;     // 0,15,31,47
    const size_t sb = (size_t)bc*2048;    // uints per bc slice
    for (int i = tid; i < 576; i += 256){
        int r = i >> 5, cu = i & 31;
        int ridx = ybase + r; if (ridx > 63) ridx = 63;
        unsigned u = attn_u[sb + ridx*32 + cu];
        sA[r*65 + cu*2]   = bflo(u);
        sA[r*65 + cu*2+1] = bfhi(u);
    }
    __syncthreads();
    const float rr = 63.0f/127.0f;
    const int ro = tid >> 3, cbase = tid & 7;
    const int yo = qy*32 + ro;
    float ty = yo * rr;
    int y0 = (int)ty; y0 = y0 > 62 ? 62 : y0;
    float wy = ty - (float)y0;
    const float* ra = &sA[(y0 - ybase)*65];
    const float* rb = ra + 65;
    float* orow = &out[((size_t)bc*128 + yo)*128];
    #pragma unroll
    for (int t = 0; t < 4; ++t){
        int xo0 = (cbase + t*8)*4;
        float4 o;
        float* op = (float*)&o;
        #pragma unroll
        for (int j = 0; j < 4; ++j){
            int xo = xo0 + j;
            float tx = xo * rr;
            int x0 = (int)tx; x0 = x0 > 62 ? 62 : x0;
            float wx = tx - (float)x0;
            float a00 = ra[x0], a01 = ra[x0+1];
            float a10 = rb[x0], a11 = rb[x0+1];
            float v = (a00*(1.f-wy) + a10*wy)*(1.f-wx) + (a01*(1.f-wy) + a11*wy)*wx;
            op[j] = 1.0f/(1.0f + expf(-v));
        }
        *(float4*)&orow[xo0] = o;
    }
}

extern "C" void kernel_launch(void* const* d_in, const int* in_sizes, int n_in,
                              void* d_out, int out_size, void* d_ws, size_t ws_size,
                              hipStream_t stream){
    const float* in1  = (const float*)d_in[0];
    const float* in2  = (const float*)d_in[1];
    const float* w_in = (const float*)d_in[2];
    const float* b_in = (const float*)d_in[3];
    const float* w_v  = (const float*)d_in[4];
    const float* b_v  = (const float*)d_in[5];
    const float* scp  = (const float*)d_in[6];
    const float* pos1 = (const float*)d_in[7];
    const float* pos2 = (const float*)d_in[8];
    float* out = (float*)d_out;
    char* ws  = (char*)d_ws;

    const size_t PBYTES = (size_t)8*4096*512*2;   // 33.55 MB per bf16 (b,n,c) buffer
    unsigned short* p1t  = (unsigned short*)ws;                 // qfoc in-place after k_rows
    unsigned short* p2t  = (unsigned short*)(ws + PBYTES);      // pooled projected input2 == v
    unsigned short* kfoc = (unsigned short*)(ws + 2*PBYTES);    // focused k; reused as attn (b,c,n)
    float*          kvb  = (float*)(ws + 3*PBYTES);             // 512 KB
    unsigned*       wbf  = (unsigned*)(ws + 3*PBYTES + (size_t)8*16*32*32*4);  // 256 KB bf16 w_in

    hipMemsetAsync(kvb, 0, (size_t)8*16*32*32*sizeof(float), stream);
    k_wprep   <<<64,            256, 0, stream>>>(w_in, wbf);
    k_pool1   <<<dim3(64,16,8), 256, 0, stream>>>(in1, (unsigned*)p1t);
    k_convpool<<<dim3(128,4,8), 256, 0, stream>>>(in2, wbf, b_in, p2t);
    k_rows    <<<dim3(2048,8),  256, 0, stream>>>((unsigned*)p1t, (const unsigned*)p2t, pos1, pos2, scp, (unsigned*)kfoc);
    k_kv      <<<dim3(16,16,8), 256, 0, stream>>>((const unsigned*)kfoc, (const unsigned*)p2t, kvb);
    k_attn    <<<dim3(64,16,8), 256, 0, stream>>>((const unsigned*)p1t, (const unsigned*)p2t, kvb, w_v, b_v, kfoc);
    k_up      <<<dim3(4,4096),  256, 0, stream>>>((const unsigned*)kfoc, out);
}